// Round 5
// baseline (804.515 us; speedup 1.0000x reference)
//
#include <hip/hip_runtime.h>

// LatentDynamicsModel fused: in-proj + GRU cell + out-proj.
// I/O fp32; internal GEMM math bf16 MFMA with fp32 accum.
// B=131072, HID=256, LATENT=64, ACTION=2.
// v6 "fat waves": 256-thread blocks (4 waves), BM=64, __launch_bounds__(256,2)
//   -> 2 blocks/CU, 2 waves/SIMD (from DIFFERENT blocks: barrier-decoupled),
//      256 regs/wave. Stage B processes 2 output tiles per K-sweep (128 acc
//      in AGPRs) with ~60 VGPR of weight-frag prefetch headroom -> the L2
//      weight latency (the v5 stall, Little's law needs ~15 frags in flight)
//      is finally hideable. A-frag LDS traffic halves (24 MFMA per 4 reads).
// Weights frag-linear in ws (prep unchanged from v4/v5); xh frag-linear LDS.

typedef unsigned short u16;
typedef unsigned int u32;
using bf16x8 = __attribute__((ext_vector_type(8))) short;  // 8 bf16 (4 VGPRs)
using f32x4  = __attribute__((ext_vector_type(4))) float;  // 4 fp32 acc
using u16x4  = __attribute__((ext_vector_type(4))) unsigned short;

constexpr int B_TOT = 131072;
constexpr int BM    = 64;    // batch rows per block

// frag-linear ws layout (u16 units). A (tile,kc) block = 64 lanes x 8 u16 = 512.
constexpr int OFF_WIN = 0;                  // 16 tiles x 2 kc x 512 = 16384
constexpr int OFF_WG  = 16384;              // 48 gate-tiles x 16 kc x 512 ([Wih|Whh] per gate r,z,n)
constexpr int OFF_WO1 = 409600;             // 16 tiles x 8 kc x 512 = 65536
constexpr int OFF_WO2 = 475136;             // 4 tiles x 8 kc x 512 = 16384
constexpr int WS_TOT  = 491520;

__device__ __forceinline__ u16 f2b(float f) {  // RNE float->bf16 (scalar fallback)
    u32 u = __builtin_bit_cast(u32, f);
    return (u16)((u + 0x7FFFu + ((u >> 16) & 1u)) >> 16);
}
__device__ __forceinline__ u32 pkbf(float lo, float hi) {  // HW RNE pack: [bf16(lo) | bf16(hi)<<16]
    u32 r;
    asm("v_cvt_pk_bf16_f32 %0, %1, %2" : "=v"(r) : "v"(lo), "v"(hi));
    return r;
}
__device__ __forceinline__ float sigm(float x) {
    x = fminf(fmaxf(x, -30.f), 30.f);
    float e = __expf(x);
    return e * __builtin_amdgcn_rcpf(1.f + e);
}
__device__ __forceinline__ float tanh_(float x) {
    x = fminf(fmaxf(x, -15.f), 15.f);
    float e = __expf(2.f * x);
    return (e - 1.f) * __builtin_amdgcn_rcpf(e + 1.f);
}
__device__ __forceinline__ bf16x8 ld8f_bf(const float* __restrict__ p) {
    float4 a = *reinterpret_cast<const float4*>(p);
    float4 b = *reinterpret_cast<const float4*>(p + 4);
    union { u32 u[4]; bf16x8 v; } q;
    q.u[0] = pkbf(a.x, a.y); q.u[1] = pkbf(a.z, a.w);
    q.u[2] = pkbf(b.x, b.y); q.u[3] = pkbf(b.z, b.w);
    return q.v;
}
__device__ __forceinline__ float b2f(u16 u) {
    u32 x = (u32)u << 16;
    return __builtin_bit_cast(float, x);
}
// scalar element (row 0..63, virtual-k 0..511; x cols = 0..255, h cols = 256..511)
__device__ __forceinline__ int fidx(int row, int kv) {
    return ((row >> 4) * 16 + (kv >> 5)) * 512 + ((kv >> 3) & 3) * 128 + (row & 15) * 8 + (kv & 7);
}

#define MFMA(a, b, c) __builtin_amdgcn_mfma_f32_16x16x32_bf16((a), (b), (c), 0, 0, 0)

// ---------- prep: fp32 -> bf16 + swizzle into MFMA B-frag linear layout ----------
// Frag element (tile, kc, lane, e) holds W[tile*16 + (lane&15)][kc*32 + (lane>>4)*8 + e].
__global__ void ldm_prep(const float* __restrict__ W_in, const float* __restrict__ W_ih,
                         const float* __restrict__ W_hh, const float* __restrict__ W_o1,
                         const float* __restrict__ W_o2, u16* __restrict__ ws)
{
    int i = blockIdx.x * blockDim.x + threadIdx.x;
    if (i >= WS_TOT) return;
    const int lane = (i >> 3) & 63;
    const int e    = i & 7;
    const int lrow = lane & 15;
    const int kq   = (lane >> 4) * 8 + e;     // k offset within the 32-wide kc block
    float v;
    if (i < OFF_WG) {                          // W_in (K=64, 2 kc blocks per tile)
        const int blk = i >> 9;
        const int kc = blk & 1, t = blk >> 1;
        v = W_in[(t * 16 + lrow) * 66 + kc * 32 + kq];
    } else if (i < OFF_WO1) {                  // gates: [Wih | Whh], K=512 (16 kc blocks)
        const int j = i - OFF_WG;
        const int blk = j >> 9;
        const int kc16 = blk & 15, gt = blk >> 4;
        const int g = gt >> 4, t = gt & 15;
        const int grow = g * 256 + t * 16 + lrow;
        const int k = (kc16 & 7) * 32 + kq;
        v = (kc16 < 8) ? W_ih[grow * 256 + k] : W_hh[grow * 256 + k];
    } else if (i < OFF_WO2) {                  // W_o1 (K=256, 8 kc blocks)
        const int j = i - OFF_WO1;
        const int blk = j >> 9;
        const int kc = blk & 7, t = blk >> 3;
        v = W_o1[(t * 16 + lrow) * 256 + kc * 32 + kq];
    } else {                                   // W_o2 (64 rows, K=256)
        const int j = i - OFF_WO2;
        const int blk = j >> 9;
        const int kc = blk & 7, t = blk >> 3;
        v = W_o2[(t * 16 + lrow) * 256 + kc * 32 + kq];
    }
    ws[i] = f2b(v);
}

// ---------- main fused kernel ----------
__global__ __launch_bounds__(256, 2)
void ldm_fused(const float* __restrict__ z, const float* __restrict__ act,
               const float* __restrict__ hid,
               const float* __restrict__ W_in_f, const float* __restrict__ b_in,
               const float* __restrict__ b_ih, const float* __restrict__ b_hh,
               const float* __restrict__ b_o1, const float* __restrict__ b_o2,
               const u16* __restrict__ ws,
               float* __restrict__ zn_out, float* __restrict__ h_out)
{
    // merged frag-linear activation buffer: virtual-k 0..255 = x, 256..511 = h (64KB)
    __shared__ u16 xh[4 * 16 * 512];

    const int tid  = threadIdx.x;
    const int w    = tid >> 6;      // wave 0..3 (owns cols [w*64, w*64+64))
    const int lane = tid & 63;
    const int l16  = lane & 15;
    const int quad = lane >> 4;
    const int row0 = blockIdx.x * BM;
    const int lofs = lane * 8;      // u16 offset of this lane's frag slot

    // ---- issue cooperative hidden load early (64 rows x 256 f32 = 64KB) ----
    // thread -> row tid>>2, 64 consecutive cols at (tid&3)*64 (16x float4)
    const int hr  = tid >> 2;
    const int hc0 = (tid & 3) * 64;
    float4 hregA[8], hregB[8];
    {
        const float* hp = hid + (size_t)(row0 + hr) * 256 + hc0;
        #pragma unroll
        for (int i = 0; i < 8; ++i) hregA[i] = reinterpret_cast<const float4*>(hp)[i];
        #pragma unroll
        for (int i = 0; i < 8; ++i) hregB[i] = reinterpret_cast<const float4*>(hp)[8 + i];
    }

    // ================= Stage A: x = relu([z|action] @ W_in^T + b_in) =================
    {
        bf16x8 az[4][2];  // [m-tile][k-chunk]
        #pragma unroll
        for (int mt = 0; mt < 4; ++mt) {
            const float* zp = z + (size_t)(row0 + mt * 16 + l16) * 64 + quad * 8;
            az[mt][0] = ld8f_bf(zp);
            az[mt][1] = ld8f_bf(zp + 32);
        }
        #pragma unroll
        for (int ot = 0; ot < 4; ++ot) {
            const int T = w * 4 + ot;
            const int orow = T * 16 + l16;  // output col / W_in row
            bf16x8 bw[2];
            #pragma unroll
            for (int kc = 0; kc < 2; ++kc)
                bw[kc] = *reinterpret_cast<const bf16x8*>(ws + OFF_WIN + (T * 2 + kc) * 512 + lofs);
            f32x4 acc[4];
            #pragma unroll
            for (int mt = 0; mt < 4; ++mt) acc[mt] = {0.f, 0.f, 0.f, 0.f};
            #pragma unroll
            for (int kc = 0; kc < 2; ++kc)
                #pragma unroll
                for (int mt = 0; mt < 4; ++mt)
                    acc[mt] = MFMA(az[mt][kc], bw[kc], acc[mt]);
            const float w64v = W_in_f[orow * 66 + 64];
            const float w65v = W_in_f[orow * 66 + 65];
            const float bi   = b_in[orow];
            #pragma unroll
            for (int mt = 0; mt < 4; ++mt) {
                #pragma unroll
                for (int i = 0; i < 4; ++i) {
                    const int rl = mt * 16 + quad * 4 + i;
                    const float2 av = reinterpret_cast<const float2*>(act)[row0 + rl];
                    float v = acc[mt][i] + av.x * w64v + av.y * w65v + bi;
                    xh[fidx(rl, orow)] = f2b(fmaxf(v, 0.f));
                }
            }
        }
    }

    // ---- hidden -> LDS (bf16, frag layout, virtual-k 256+c) ----
    {
        #pragma unroll
        for (int i = 0; i < 8; ++i) {
            union { u32 u[2]; u16x4 v; } q;
            q.u[0] = pkbf(hregA[i].x, hregA[i].y);
            q.u[1] = pkbf(hregA[i].z, hregA[i].w);
            *reinterpret_cast<u16x4*>(&xh[fidx(hr, 256 + hc0 + i * 4)]) = q.v;
        }
        #pragma unroll
        for (int i = 0; i < 8; ++i) {
            union { u32 u[2]; u16x4 v; } q;
            q.u[0] = pkbf(hregB[i].x, hregB[i].y);
            q.u[1] = pkbf(hregB[i].z, hregB[i].w);
            *reinterpret_cast<u16x4*>(&xh[fidx(hr, 256 + hc0 + 32 + i * 4)]) = q.v;
        }
    }
    __syncthreads();

    // ================= Stage B: GRU gates, 2 tiles per K-sweep (merged pair) =======
    // Streams (frag-linear): WR/WZ full K=512 ([Wih_g | Whh_g]); WN: kc0..7 = Wih_n
    // (-> gNi), kc8..15 = Whh_n (-> gNh). 4 A-frags per kc shared by 24 MFMAs.
    u32 hnpA[8], hnpB[8], hnpC[8], hnpD[8];   // h_new bf16 packed, tiles 0..3

    auto epi = [&](const int T, const f32x4 (&R)[4], const f32x4 (&Zg)[4],
                   const f32x4 (&Ni)[4], const f32x4 (&Nh)[4], u32 (&pk)[8]) {
        const int o = T * 16 + l16;
        const float br_b = b_ih[o]       + b_hh[o];
        const float bz_b = b_ih[o + 256] + b_hh[o + 256];
        const float bni  = b_ih[o + 512];
        const float bnh  = b_hh[o + 512];
        #pragma unroll
        for (int mt = 0; mt < 4; ++mt) {
            float hn[4];
            #pragma unroll
            for (int i = 0; i < 4; ++i) {
                const int rl = mt * 16 + quad * 4 + i;
                const float hv = b2f(xh[fidx(rl, 256 + o)]);
                const float r  = sigm(R[mt][i] + br_b);
                const float zg = sigm(Zg[mt][i] + bz_b);
                const float n  = tanh_(Ni[mt][i] + bni + r * (Nh[mt][i] + bnh));
                hn[i] = n + zg * (hv - n);
            }
            pk[mt * 2]     = pkbf(hn[0], hn[1]);
            pk[mt * 2 + 1] = pkbf(hn[2], hn[3]);
        }
    };

    auto gru_pair = [&](const int p, u32 (&pk0)[8], u32 (&pk1)[8]) {
        const int T0 = w * 4 + p * 2;
        const int T1 = T0 + 1;
        const u16* WR0 = ws + OFF_WG + (size_t)((0  + T0) * 16) * 512 + lofs;
        const u16* WR1 = ws + OFF_WG + (size_t)((0  + T1) * 16) * 512 + lofs;
        const u16* WZ0 = ws + OFF_WG + (size_t)((16 + T0) * 16) * 512 + lofs;
        const u16* WZ1 = ws + OFF_WG + (size_t)((16 + T1) * 16) * 512 + lofs;
        const u16* WN0 = ws + OFF_WG + (size_t)((32 + T0) * 16) * 512 + lofs;
        const u16* WN1 = ws + OFF_WG + (size_t)((32 + T1) * 16) * 512 + lofs;

        f32x4 gR[2][4], gZ[2][4], gNi[2][4], gNh[2][4];   // 128 acc regs (AGPR)
        #pragma unroll
        for (int tt = 0; tt < 2; ++tt)
            #pragma unroll
            for (int mt = 0; mt < 4; ++mt) {
                gR[tt][mt]  = {0.f, 0.f, 0.f, 0.f};
                gZ[tt][mt]  = {0.f, 0.f, 0.f, 0.f};
                gNi[tt][mt] = {0.f, 0.f, 0.f, 0.f};
                gNh[tt][mt] = {0.f, 0.f, 0.f, 0.f};
            }

        #pragma unroll
        for (int kc = 0; kc < 16; ++kc) {
            const bf16x8 wr0 = *reinterpret_cast<const bf16x8*>(WR0 + kc * 512);
            const bf16x8 wr1 = *reinterpret_cast<const bf16x8*>(WR1 + kc * 512);
            const bf16x8 wz0 = *reinterpret_cast<const bf16x8*>(WZ0 + kc * 512);
            const bf16x8 wz1 = *reinterpret_cast<const bf16x8*>(WZ1 + kc * 512);
            const bf16x8 wn0 = *reinterpret_cast<const bf16x8*>(WN0 + kc * 512);
            const bf16x8 wn1 = *reinterpret_cast<const bf16x8*>(WN1 + kc * 512);
            #pragma unroll
            for (int mt = 0; mt < 4; ++mt) {
                const bf16x8 am = *reinterpret_cast<const bf16x8*>(&xh[(mt * 16 + kc) * 512 + lofs]);
                gR[0][mt] = MFMA(am, wr0, gR[0][mt]);
                gR[1][mt] = MFMA(am, wr1, gR[1][mt]);
                gZ[0][mt] = MFMA(am, wz0, gZ[0][mt]);
                gZ[1][mt] = MFMA(am, wz1, gZ[1][mt]);
                if (kc < 8) {
                    gNi[0][mt] = MFMA(am, wn0, gNi[0][mt]);
                    gNi[1][mt] = MFMA(am, wn1, gNi[1][mt]);
                } else {
                    gNh[0][mt] = MFMA(am, wn0, gNh[0][mt]);
                    gNh[1][mt] = MFMA(am, wn1, gNh[1][mt]);
                }
            }
        }

        epi(T0, gR[0], gZ[0], gNi[0], gNh[0], pk0);
        epi(T1, gR[1], gZ[1], gNi[1], gNh[1], pk1);
    };

    gru_pair(0, hnpA, hnpB);
    gru_pair(1, hnpC, hnpD);

    __syncthreads();   // all reads of x and old-h complete

    // scatter h_new into the h region (overwrite old h)
    auto scat = [&](const int q, const u32 (&pk)[8]) {
        const int o = (w * 4 + q) * 16 + l16;
        #pragma unroll
        for (int mt = 0; mt < 4; ++mt) {
            #pragma unroll
            for (int p = 0; p < 2; ++p) {
                const u32 v = pk[mt * 2 + p];
                const int rl = mt * 16 + quad * 4 + p * 2;
                xh[fidx(rl,     256 + o)] = (u16)v;
                xh[fidx(rl + 1, 256 + o)] = (u16)(v >> 16);
            }
        }
    };
    scat(0, hnpA);
    scat(1, hnpB);
    scat(2, hnpC);
    scat(3, hnpD);
    __syncthreads();

    // coalesced h_new -> global (bf16 LDS frag layout -> fp32 stores)
    #pragma unroll
    for (int it = 0; it < 8; ++it) {
        const int idx = it * 2048 + tid * 8;
        const int r = idx >> 8, c = idx & 255;
        const bf16x8 v = *reinterpret_cast<const bf16x8*>(&xh[fidx(r, 256 + c)]);
        float4 f0, f1;
        f0.x = b2f((u16)v[0]); f0.y = b2f((u16)v[1]); f0.z = b2f((u16)v[2]); f0.w = b2f((u16)v[3]);
        f1.x = b2f((u16)v[4]); f1.y = b2f((u16)v[5]); f1.z = b2f((u16)v[6]); f1.w = b2f((u16)v[7]);
        float* dst = h_out + (size_t)(row0 + r) * 256 + c;
        *reinterpret_cast<float4*>(dst)     = f0;
        *reinterpret_cast<float4*>(dst + 4) = f1;
    }

    // ================= Stage 4: y = relu(h_new @ W_o1^T + b_o1) -> x region =================
    #pragma unroll 1
    for (int ot = 0; ot < 4; ++ot) {
        const int T = w * 4 + ot;
        const int o = T * 16 + l16;
        f32x4 aY[4];
        #pragma unroll
        for (int mt = 0; mt < 4; ++mt) aY[mt] = {0.f, 0.f, 0.f, 0.f};
        bf16x8 wo[8];
        #pragma unroll
        for (int kc = 0; kc < 8; ++kc)
            wo[kc] = *reinterpret_cast<const bf16x8*>(ws + OFF_WO1 + (T * 8 + kc) * 512 + lofs);
        #pragma unroll
        for (int kc = 0; kc < 8; ++kc) {
            bf16x8 ah2[4];
            #pragma unroll
            for (int mt = 0; mt < 4; ++mt)
                ah2[mt] = *reinterpret_cast<const bf16x8*>(&xh[(mt * 16 + 8 + kc) * 512 + lofs]);
            #pragma unroll
            for (int mt = 0; mt < 4; ++mt)
                aY[mt] = MFMA(ah2[mt], wo[kc], aY[mt]);
        }
        const float bo1 = b_o1[o];
        #pragma unroll
        for (int mt = 0; mt < 4; ++mt)
            #pragma unroll
            for (int i = 0; i < 4; ++i) {
                const int rl = mt * 16 + quad * 4 + i;
                xh[fidx(rl, o)] = f2b(fmaxf(aY[mt][i] + bo1, 0.f));
            }
    }
    __syncthreads();

    // ================= Stage 5: z_next = y @ W_o2^T + b_o2 (LDS-transposed store) ==
    {
        const int o = w * 16 + l16;      // wave w owns zn col-tile w (4 x 16 = 64 cols)
        f32x4 aO[4];
        #pragma unroll
        for (int mt = 0; mt < 4; ++mt) aO[mt] = {0.f, 0.f, 0.f, 0.f};
        bf16x8 wo2[8];
        #pragma unroll
        for (int kc = 0; kc < 8; ++kc)
            wo2[kc] = *reinterpret_cast<const bf16x8*>(ws + OFF_WO2 + (w * 8 + kc) * 512 + lofs);
        #pragma unroll
        for (int kc = 0; kc < 8; ++kc) {
            #pragma unroll
            for (int mt = 0; mt < 4; ++mt) {
                const bf16x8 ay = *reinterpret_cast<const bf16x8*>(&xh[(mt * 16 + kc) * 512 + lofs]);
                aO[mt] = MFMA(ay, wo2[kc], aO[mt]);
            }
        }
        const float bz2 = b_o2[o];

        __syncthreads();                 // all y reads done; xh reusable as f32 scratch
        float* zsc = reinterpret_cast<float*>(xh);   // 64 rows x stride 68 f32 (17.4KB)
        #pragma unroll
        for (int mt = 0; mt < 4; ++mt)
            #pragma unroll
            for (int i = 0; i < 4; ++i) {
                const int rl = mt * 16 + quad * 4 + i;
                zsc[rl * 68 + o] = aO[mt][i] + bz2;
            }
        __syncthreads();
        const int zr = tid >> 2, zc = (tid & 3) * 16;
        float* dst = zn_out + (size_t)(row0 + zr) * 64 + zc;
        #pragma unroll
        for (int j = 0; j < 4; ++j) {
            float4 zv = *reinterpret_cast<const float4*>(&zsc[zr * 68 + zc + j * 4]);
            *reinterpret_cast<float4*>(dst + j * 4) = zv;
        }
    }
}

extern "C" void kernel_launch(void* const* d_in, const int* in_sizes, int n_in,
                              void* d_out, int out_size, void* d_ws, size_t ws_size,
                              hipStream_t stream) {
    const float* z    = (const float*)d_in[0];
    const float* act  = (const float*)d_in[1];
    const float* hid  = (const float*)d_in[2];
    const float* W_in = (const float*)d_in[3];
    const float* b_in = (const float*)d_in[4];
    const float* W_ih = (const float*)d_in[5];
    const float* W_hh = (const float*)d_in[6];
    const float* b_ih = (const float*)d_in[7];
    const float* b_hh = (const float*)d_in[8];
    const float* W_o1 = (const float*)d_in[9];
    const float* b_o1 = (const float*)d_in[10];
    const float* W_o2 = (const float*)d_in[11];
    const float* b_o2 = (const float*)d_in[12];

    u16* ws = (u16*)d_ws;

    float* zn_out = (float*)d_out;                      // [B, 64]
    float* h_out  = zn_out + (size_t)B_TOT * 64;        // [1, B, 256]

    ldm_prep<<<dim3((WS_TOT + 255) / 256), dim3(256), 0, stream>>>(
        W_in, W_ih, W_hh, W_o1, W_o2, ws);

    ldm_fused<<<dim3(B_TOT / BM), dim3(256), 0, stream>>>(
        z, act, hid, W_in, b_in, b_ih, b_hh, b_o1, b_o2, ws, zn_out, h_out);
}